// Round 12
// baseline (337.537 us; speedup 1.0000x reference)
//
#include <hip/hip_runtime.h>
#include <math.h>

// ---------------------------------------------------------------------------
#define B_ROWS   8192
#define NZ       100
#define NC       2
#define H1       256
#define H2       64
#define FEATN    8192
#define FDIM     1024
#define RROWS    16            // rows per k_main block = MFMA M
#define NTILE    (FEATN / 16)  // 512 16-col MFMA tiles
#define A1ROWS   16
#define A1BLKS   (B_ROWS / A1ROWS)   // 512
#define CONVBLKS 256                 // w3 conversion blocks fused into k_a1
#define A2BLKS   (B_ROWS / 4)        // 2048

typedef __attribute__((ext_vector_type(8))) short short8;
typedef __attribute__((ext_vector_type(4))) float f32x4;

// ---------------------------------------------------------------------------
// JAX threefry2x32, partitionable, key=(0,42), counter=(0, flat)
__device__ __forceinline__ unsigned rotl32(unsigned v, int r) {
    return (v << r) | (v >> (32 - r));
}
__device__ __forceinline__ unsigned threefry_bits(unsigned lo) {
    const unsigned ks0 = 0u, ks1 = 42u, ks2 = 0x1BD11BDAu ^ 42u;
    unsigned x0 = 0u + ks0;
    unsigned x1 = lo + ks1;
#define TF_R4(a,b,c,d) \
    x0 += x1; x1 = rotl32(x1,a); x1 ^= x0; \
    x0 += x1; x1 = rotl32(x1,b); x1 ^= x0; \
    x0 += x1; x1 = rotl32(x1,c); x1 ^= x0; \
    x0 += x1; x1 = rotl32(x1,d); x1 ^= x0;
    TF_R4(13,15,26,6);  x0 += ks1; x1 += ks2 + 1u;
    TF_R4(17,29,16,24); x0 += ks2; x1 += ks0 + 2u;
    TF_R4(13,15,26,6);  x0 += ks0; x1 += ks1 + 3u;
    TF_R4(17,29,16,24); x0 += ks1; x1 += ks2 + 4u;
    TF_R4(13,15,26,6);  x0 += ks2; x1 += ks0 + 5u;
#undef TF_R4
    return x0 ^ x1;
}
__device__ __forceinline__ float gumbel_g(unsigned flat) {
    unsigned bits = threefry_bits(flat);
    float u  = __uint_as_float((bits >> 9) | 0x3f800000u) - 1.0f;
    float U  = 0.001f * u;
    float t1 = U + 0.001f;
    float L1 = (float)log((double)t1);
    float A  = 0.001f - L1;
    float L2 = (float)log((double)A);
    return -L2;
}

// float -> bf16 RNE
__device__ __forceinline__ unsigned short f2bf(float x) {
    unsigned u = __float_as_uint(x);
    u += 0x7fffu + ((u >> 16) & 1u);
    return (unsigned short)(u >> 16);
}
// order-preserving float -> u32
__device__ __forceinline__ unsigned fmono(float x) {
    unsigned b = __float_as_uint(x);
    return (b & 0x80000000u) ? ~b : (b | 0x80000000u);
}
// scale/shift from global f64 sums (identical ops in every consumer block)
__device__ __forceinline__ void bn_fold(double s, double s2,
                                        float gamma, float beta,
                                        float* scale, float* shift) {
    double mean = s * (1.0 / B_ROWS);
    double var  = s2 * (1.0 / B_ROWS) - mean * mean;
    double rstd = 1.0 / sqrt(var + 1e-5);
    double sc   = (double)gamma * rstd;
    *scale = (float)sc;
    *shift = (float)((double)beta - mean * sc);
}

// ---------------------------------------------------------------------------
// K1: blocks [0,A1BLKS): a1 = concat(x,y)@W1 + b1 (fp64) + BN1 sums via
//     f64 atomicAdd. blocks [A1BLKS,..): W3 -> bf16 MFMA-B layout + max|W3|.
__global__ __launch_bounds__(256) void k_a1(
    const float* __restrict__ x, const float* __restrict__ y,
    const float* __restrict__ W1, const float* __restrict__ b1,
    const float* __restrict__ W3,
    float* __restrict__ a1,
    double* __restrict__ sum1, double* __restrict__ sum2,   // [H1]
    unsigned short* __restrict__ w3s, float* __restrict__ maxw)
{
    const int t = threadIdx.x;

    if (blockIdx.x >= A1BLKS) {
        const int job  = (blockIdx.x - A1BLKS) * 256 + t;   // 0..65535
        const int T    = job >> 7;
        const int rem  = job & 127;
        const int kh   = rem >> 6;
        const int l    = rem & 63;
        const int quad = l >> 4, col = l & 15;
        const float* src = W3 + (size_t)(kh * 32 + quad * 8) * FEATN + T * 16 + col;
        unsigned short v[8];
        float mx = 0.0f;
#pragma unroll
        for (int jj = 0; jj < 8; ++jj) {
            float xv = src[(size_t)jj * FEATN];
            mx = fmaxf(mx, fabsf(xv));
            v[jj] = f2bf(xv);
        }
        uint4 o;
        o.x = (unsigned)v[0] | ((unsigned)v[1] << 16);
        o.y = (unsigned)v[2] | ((unsigned)v[3] << 16);
        o.z = (unsigned)v[4] | ((unsigned)v[5] << 16);
        o.w = (unsigned)v[6] | ((unsigned)v[7] << 16);
        ((uint4*)w3s)[job] = o;
#pragma unroll
        for (int off = 32; off; off >>= 1) mx = fmaxf(mx, __shfl_xor(mx, off));
        __shared__ float wred[4];
        if ((t & 63) == 0) wred[t >> 6] = mx;
        __syncthreads();
        if (t == 0) {
            float m = fmaxf(fmaxf(wred[0], wred[1]), fmaxf(wred[2], wred[3]));
            atomicMax((unsigned*)maxw, __float_as_uint(m));
        }
        return;
    }

    const int j  = t;
    const int b0 = blockIdx.x * A1ROWS;
    double acc[A1ROWS];
#pragma unroll
    for (int r = 0; r < A1ROWS; ++r) acc[r] = 0.0;
    for (int i = 0; i < NZ; ++i) {
        float w = W1[i * H1 + j];
#pragma unroll
        for (int r = 0; r < A1ROWS; ++r)
            acc[r] += (double)x[(b0 + r) * NZ + i] * (double)w;
    }
#pragma unroll
    for (int i = 0; i < NC; ++i) {
        float w = W1[(NZ + i) * H1 + j];
#pragma unroll
        for (int r = 0; r < A1ROWS; ++r)
            acc[r] += (double)y[(b0 + r) * NC + i] * (double)w;
    }
    double bb = (double)b1[j];
    double s = 0.0, s2 = 0.0;
#pragma unroll
    for (int r = 0; r < A1ROWS; ++r) {
        float v = (float)(acc[r] + bb);
        a1[(b0 + r) * H1 + j] = v;
        double dv = (double)v;
        s += dv; s2 += dv * dv;
    }
    atomicAdd(&sum1[j], s);     // native f64 global atomic on CDNA
    atomicAdd(&sum2[j], s2);
}

// ---------------------------------------------------------------------------
// K2: derive sc1/sh1 from global sums (per block, cheap); a2 = relu(bn(a1))@W2
//     + b2 (fp64 acc); BN2 sums via f64 atomicAdd.
__global__ __launch_bounds__(256) void k_a2(
    const float* __restrict__ a1,
    const double* __restrict__ sum1, const double* __restrict__ sum2,
    const float* __restrict__ g1, const float* __restrict__ be1,
    const float* __restrict__ W2, const float* __restrict__ b2,
    float* __restrict__ a2,
    double* __restrict__ sum3, double* __restrict__ sum4)   // [H2]
{
    const int t  = threadIdx.x;
    __shared__ float lsc[H1], lsh[H1];
    bn_fold(sum1[t], sum2[t], g1[t], be1[t], &lsc[t], &lsh[t]);
    __syncthreads();

    const int k  = t & 63;
    const int rr = t >> 6;
    const int b  = blockIdx.x * 4 + rr;
    double acc = 0.0;
    for (int j = 0; j < H1; ++j) {
        float h = fmaxf(fmaf(a1[b * H1 + j], lsc[j], lsh[j]), 0.0f);
        acc += (double)h * (double)W2[j * H2 + k];
    }
    float v = (float)(acc + (double)b2[k]);
    a2[b * H2 + k] = v;

    __shared__ double ls[256], ls2[256];
    ls[t]  = (double)v;
    ls2[t] = (double)v * (double)v;
    __syncthreads();
    if (t < 64) {
        double s  = (ls[t]  + ls[t + 64])  + (ls[t + 128]  + ls[t + 192]);
        double s2 = (ls2[t] + ls2[t + 64]) + (ls2[t + 128] + ls2[t + 192]);
        atomicAdd(&sum3[t], s);
        atomicAdd(&sum4[t], s2);
    }
}

// ---------------------------------------------------------------------------
// K5: derive sc2/sh2 from global sums; pass A = bf16 MFMA bounds; worklist
// pass B = exact fp32; winner via packed u64 LDS atomicMax; codebook gather.
__global__ __launch_bounds__(512)
__attribute__((amdgpu_waves_per_eu(4, 4)))
void k_main(
    const float* __restrict__ a2,
    const double* __restrict__ sum3, const double* __restrict__ sum4,
    const float* __restrict__ g2, const float* __restrict__ be2,
    const float* __restrict__ W3, const float* __restrict__ b3,
    const unsigned short* __restrict__ w3s, const float* __restrict__ maxw,
    const float* __restrict__ codebook, float* __restrict__ out)
{
    const int t    = threadIdx.x;
    const int wv   = t >> 6;           // wave 0..7
    const int lane = t & 63;
    const int quad = lane >> 4, col = lane & 15;
    const int b0   = blockIdx.x * RROWS;

    __shared__ __align__(16) float h2T[64][RROWS];  // [j][r], 4 KB
    __shared__ float sc2S[H2], sh2S[H2];
    __shared__ float fineS[RROWS][64];              // per-(row, 128-f seg) max
    __shared__ float thrS[RROWS];
    __shared__ unsigned long long best[RROWS];
    __shared__ unsigned short wl[1024];
    __shared__ int wlN;
    __shared__ int rowInd[RROWS];
    __shared__ float maxwS;

    if (t == 0) { maxwS = maxw[0]; wlN = 0; }
    if (t < H2)
        bn_fold(sum3[t], sum4[t], g2[t], be2[t], &sc2S[t], &sh2S[t]);
    __syncthreads();

    for (int q = t; q < RROWS * 64; q += 512) {
        int j = q >> 4, r = q & 15;
        float v = a2[(b0 + r) * H2 + j];
        h2T[j][r] = fmaxf(fmaf(v, sc2S[j], sh2S[j]), 0.0f);
    }
    __syncthreads();

    // A fragments (bf16): A[m=col][k=quad*8+jj], k-halves 0/1
    short8 aF0, aF1;
#pragma unroll
    for (int jj = 0; jj < 8; ++jj) {
        aF0[jj] = (short)f2bf(h2T[quad * 8 + jj][col]);
        aF1[jj] = (short)f2bf(h2T[32 + quad * 8 + jj][col]);
    }

    // ---- Pass A: 8 segments x 8 tiles per wave ----
    {
        const uint4* wp  = (const uint4*)w3s + (size_t)wv * 8192 + lane;
        const float* b3p = b3 + wv * 1024 + col;
        for (int s = 0; s < 8; ++s) {
            uint4 c[8], d[8];
            float bb[8];
#pragma unroll
            for (int u = 0; u < 8; ++u) {
                c[u]  = wp[u * 128];
                d[u]  = wp[u * 128 + 64];
                bb[u] = b3p[u * 16];
            }
            float rm0 = -1e30f, rm1 = -1e30f, rm2 = -1e30f, rm3 = -1e30f;
#pragma unroll
            for (int u = 0; u < 8; ++u) {
                f32x4 acc = {bb[u], bb[u], bb[u], bb[u]};
                acc = __builtin_amdgcn_mfma_f32_16x16x32_bf16(
                          aF0, *(const short8*)&c[u], acc, 0, 0, 0);
                acc = __builtin_amdgcn_mfma_f32_16x16x32_bf16(
                          aF1, *(const short8*)&d[u], acc, 0, 0, 0);
                rm0 = fmaxf(rm0, acc[0]); rm1 = fmaxf(rm1, acc[1]);
                rm2 = fmaxf(rm2, acc[2]); rm3 = fmaxf(rm3, acc[3]);
            }
#pragma unroll
            for (int off = 1; off < 16; off <<= 1) {
                rm0 = fmaxf(rm0, __shfl_xor(rm0, off));
                rm1 = fmaxf(rm1, __shfl_xor(rm1, off));
                rm2 = fmaxf(rm2, __shfl_xor(rm2, off));
                rm3 = fmaxf(rm3, __shfl_xor(rm3, off));
            }
            if (col == 0) {
                const int seg = wv * 8 + s;
                fineS[quad * 4 + 0][seg] = rm0;
                fineS[quad * 4 + 1][seg] = rm1;
                fineS[quad * 4 + 2][seg] = rm2;
                fineS[quad * 4 + 3][seg] = rm3;
            }
            wp += 1024; b3p += 128;
        }
    }
    __syncthreads();

    // ---- Thresholds (rigorous bf16 margin) ----
    if (t < RROWS) {
        float S = 0.0f;
        for (int j = 0; j < 64; ++j) S += fabsf(h2T[j][t]);
        float gm = -1e30f;
        for (int s = 0; s < 64; ++s) gm = fmaxf(gm, fineS[t][s]);
        float e = S * maxwS * (1.0f / 256.0f);   // |Δlogit| <= S*maxW*2^-8
        thrS[t] = gm - (0.1068f + e + 1e-3f);
        best[t] = 0ull;
    }
    __syncthreads();

    // ---- Worklist of qualifying (row, 128-f seg) cells ----
    for (int c = t; c < RROWS * 64; c += 512) {
        int r = c >> 6, seg = c & 63;
        if (fineS[r][seg] >= thrS[r]) {
            int k = atomicAdd(&wlN, 1);
            wl[k] = (unsigned short)((r << 6) | seg);
        }
    }
    __syncthreads();

    // ---- Pass B: one shared loop; wave per cell; lane per 2 f ----
    const int n = wlN;
    for (int i = wv; i < n; i += 8) {
        const int e   = wl[i];
        const int r   = e >> 6;
        const int seg = e & 63;
        const int f0  = seg * 128 + lane;
        float acc0 = b3[f0], acc1 = b3[f0 + 64];
        const float* wcol = W3 + f0;
#pragma unroll 4
        for (int j = 0; j < 64; ++j) {
            const float h = h2T[j][r];
            acc0 = fmaf(h, wcol[0],  acc0);
            acc1 = fmaf(h, wcol[64], acc1);
            wcol += FEATN;
        }
        const float th = thrS[r];
        if (acc0 >= th) {
            float sc = acc0 + gumbel_g((unsigned)(b0 + r) * (unsigned)FEATN + (unsigned)f0);
            unsigned long long pk = ((unsigned long long)fmono(sc) << 32)
                                  | (unsigned)(FEATN - 1 - f0);
            atomicMax(&best[r], pk);
        }
        if (acc1 >= th) {
            int f1 = f0 + 64;
            float sc = acc1 + gumbel_g((unsigned)(b0 + r) * (unsigned)FEATN + (unsigned)f1);
            unsigned long long pk = ((unsigned long long)fmono(sc) << 32)
                                  | (unsigned)(FEATN - 1 - f1);
            atomicMax(&best[r], pk);
        }
    }
    __syncthreads();
    if (t < RROWS) {
        rowInd[t] = (FEATN - 1 - (int)(best[t] & 0xFFFFFFFFull)) & (FEATN - 1);
    }
    __syncthreads();

    // ---- out[b,:] = codebook[ind,:] ----
    {
        const int rr = t >> 8, tt = t & 255;
        for (int rp = 0; rp < RROWS / 2; ++rp) {
            const int r = rp * 2 + rr;
            const int ind = rowInd[r];
            const float4* src = (const float4*)(codebook + (size_t)ind * FDIM);
            float4*       dst = (float4*)(out + (size_t)(b0 + r) * FDIM);
            dst[tt] = src[tt];
        }
    }
}

// ---------------------------------------------------------------------------
extern "C" void kernel_launch(void* const* d_in, const int* in_sizes, int n_in,
                              void* d_out, int out_size, void* d_ws, size_t ws_size,
                              hipStream_t stream)
{
    const float* x   = (const float*)d_in[0];
    const float* y   = (const float*)d_in[1];
    const float* W1  = (const float*)d_in[2];
    const float* b1  = (const float*)d_in[3];
    const float* g1  = (const float*)d_in[4];
    const float* be1 = (const float*)d_in[5];
    const float* W2  = (const float*)d_in[6];
    const float* b2  = (const float*)d_in[7];
    const float* g2  = (const float*)d_in[8];
    const float* be2 = (const float*)d_in[9];
    const float* W3  = (const float*)d_in[10];
    const float* b3  = (const float*)d_in[11];
    const float* cb  = (const float*)d_in[12];
    float* out = (float*)d_out;

    float* ws  = (float*)d_ws;
    float* a1  = ws;                          // 8 MB
    float* a2  = a1 + B_ROWS * H1;            // 2 MB
    double* sum1 = (double*)(a2 + B_ROWS * H2);  // 256 f64
    double* sum2 = sum1 + H1;                    // 256 f64
    double* sum3 = sum2 + H1;                    // 64 f64
    double* sum4 = sum3 + H2;                    // 64 f64
    float* maxw  = (float*)(sum4 + H2);          // 1 f32 (+pad)
    unsigned short* w3s = (unsigned short*)(maxw + 16);  // 1 MB bf16

    // zero the atomic accumulators (sums 5120 B + maxw 64 B)
    hipMemsetAsync(sum1, 0, (H1 * 2 + H2 * 2) * sizeof(double) + 64, stream);
    k_a1  <<<A1BLKS + CONVBLKS, 256, 0, stream>>>(x, y, W1, b1, W3,
                                                  a1, sum1, sum2, w3s, maxw);
    k_a2  <<<A2BLKS, 256, 0, stream>>>(a1, sum1, sum2, g1, be1, W2, b2,
                                       a2, sum3, sum4);
    k_main<<<B_ROWS / RROWS, 512, 0, stream>>>(a2, sum3, sum4, g2, be2,
                                               W3, b3, w3s, maxw, cb, out);
}